// Round 7
// baseline (193.694 us; speedup 1.0000x reference)
//
#include <hip/hip_runtime.h>
#include <hip/hip_bf16.h>
#include <hip/hip_fp16.h>

#define N_NODES 100000
#define N_EDGES 1600000
#define N_GRAPHS 64

#define NB_BKT 256      // node buckets for CSR build
#define NPBKT 391       // nodes per bucket (255*391=99705, last bucket 295)
#define EPB 2048        // edges per bin block
#define NBLK_BIN ((N_EDGES + EPB - 1) / EPB)  // 782
#define BKT_SLACK 2744  // max padding per bucket (391 nodes * 7), mult of 8

// ---------------- f16 helpers ----------------

__device__ __forceinline__ __half2 u2h(unsigned int u) {
    return __builtin_bit_cast(__half2, u);
}
__device__ __forceinline__ float2 u2f2(unsigned int u) {
    return __half22float2(u2h(u));
}
__device__ __forceinline__ unsigned int packh2(float a, float b) {
    return __builtin_bit_cast(unsigned int, __float22half2_rn(make_float2(a, b)));
}

// ---------------- CSR build: bucket-binned, LDS-staged, no global atomics ----------------

__global__ __launch_bounds__(256) void bin_count(const int* __restrict__ dst,
                                                 int* __restrict__ cntmat, int E) {
    __shared__ int cnt[NB_BKT];
    int t = threadIdx.x;
    int e0 = blockIdx.x * EPB;
    cnt[t] = 0;
    __syncthreads();
#pragma unroll
    for (int k = 0; k < 8; ++k) {
        int e = e0 + k * 256 + t;
        if (e < E) {
            unsigned d = (unsigned)dst[e];
            atomicAdd(&cnt[d / (unsigned)NPBKT], 1);
        }
    }
    __syncthreads();
    cntmat[(size_t)blockIdx.x * NB_BKT + t] = cnt[t];
}

__global__ __launch_bounds__(256) void bin_scan(int* __restrict__ cntmat,
                                                int* __restrict__ gcnt, int nblk) {
    __shared__ int s[256];
    int b = blockIdx.x, t = threadIdx.x;
    int running = 0;
    for (int c0 = 0; c0 < nblk; c0 += 256) {
        int idx = c0 + t;
        int v = (idx < nblk) ? cntmat[(size_t)idx * NB_BKT + b] : 0;
        s[t] = v;
        __syncthreads();
        for (int o = 1; o < 256; o <<= 1) {
            int a = (t >= o) ? s[t - o] : 0;
            __syncthreads();
            s[t] += a;
            __syncthreads();
        }
        if (idx < nblk) cntmat[(size_t)idx * NB_BKT + b] = running + s[t] - v;
        running += s[255];
        __syncthreads();
    }
    if (t == 0) gcnt[b] = running;
}

// Regroup edges by bucket in LDS, write records bucket-contiguous (true layout).
__global__ __launch_bounds__(256) void bin_write(const int* __restrict__ dst,
                                                 const int* __restrict__ src,
                                                 const int* __restrict__ cntmat,
                                                 const int* __restrict__ gcnt,
                                                 uint2* __restrict__ rec, int E) {
    __shared__ int cnt[NB_BKT];
    __shared__ int lbase[NB_BKT];
    __shared__ int gofs[NB_BKT];
    __shared__ uint2 stage[EPB];
    int t = threadIdx.x;
    int e0 = blockIdx.x * EPB;
    // inline exclusive scan of gcnt -> rec base per bucket
    int g = gcnt[t];
    lbase[t] = g;
    __syncthreads();
    for (int o = 1; o < 256; o <<= 1) {
        int a = (t >= o) ? lbase[t - o] : 0;
        __syncthreads();
        lbase[t] += a;
        __syncthreads();
    }
    gofs[t] = (lbase[t] - g) + cntmat[(size_t)blockIdx.x * NB_BKT + t];
    cnt[t] = 0;
    __syncthreads();
    int myb[8], mypos[8];
    unsigned myd[8], mys[8];
#pragma unroll
    for (int k = 0; k < 8; ++k) {
        int e = e0 + k * 256 + t;
        if (e < E) {
            unsigned d = (unsigned)dst[e];
            int b = (int)(d / (unsigned)NPBKT);
            myd[k] = d;
            mys[k] = (unsigned)src[e];
            myb[k] = b;
            mypos[k] = atomicAdd(&cnt[b], 1);
        } else {
            myb[k] = -1;
        }
    }
    __syncthreads();
    int c = cnt[t];
    lbase[t] = c;
    __syncthreads();
    for (int o = 1; o < 256; o <<= 1) {
        int a = (t >= o) ? lbase[t - o] : 0;
        __syncthreads();
        lbase[t] += a;
        __syncthreads();
    }
    lbase[t] = lbase[t] - c;
    __syncthreads();
#pragma unroll
    for (int k = 0; k < 8; ++k)
        if (myb[k] >= 0) stage[lbase[myb[k]] + mypos[k]] = make_uint2(myd[k], mys[k]);
    __syncthreads();
    int total = min(EPB, E - e0);
    for (int i = t; i < total; i += 256) {
        int lo = 0, hi = NB_BKT - 1;
        while (lo < hi) {
            int m = (lo + hi + 1) >> 1;
            if (lbase[m] <= i) lo = m; else hi = m - 1;
        }
        rec[(size_t)gofs[lo] + (i - lbase[lo])] = stage[i];
    }
}

// One workgroup per bucket. True deg -> deg_out; PADDED (mult-of-8) ranges -> rp.
// Pad slots point at phantom node n (zero row). col written via LDS staging.
__global__ __launch_bounds__(256) void fill_bucket(const uint2* __restrict__ rec,
                                                   const int* __restrict__ gcnt,
                                                   int* __restrict__ rp,
                                                   int* __restrict__ deg_out,
                                                   int* __restrict__ col, int n) {
    __shared__ int sdeg[512];
    __shared__ int pofs[512];
    __shared__ int lcur[512];
    __shared__ int sg[256];
    __shared__ int lcol[12288];  // 48 KB; padded bucket edges bound ~9.6k
    int p = blockIdx.x, t = threadIdx.x;
    int nbase = p * NPBKT;
    int nn = min(NPBKT, n - nbase);
    // inline exclusive scan of gcnt -> true rec base
    int g = gcnt[t];
    sg[t] = g;
    __syncthreads();
    for (int o = 1; o < 256; o <<= 1) {
        int a = (t >= o) ? sg[t - o] : 0;
        __syncthreads();
        sg[t] += a;
        __syncthreads();
    }
    int exg = sg[t] - g;
    __syncthreads();
    sg[t] = exg;
    __syncthreads();
    int rbase = sg[p];
    int cnt = gcnt[p];
    int cbase = ((rbase + 7) & ~7) + p * BKT_SLACK;  // 8-aligned col base
    // true degree count
    sdeg[t] = 0;
    sdeg[t + 256] = 0;
    __syncthreads();
    const uint2* r = rec + rbase;
    for (int i = t; i < cnt; i += 256) atomicAdd(&sdeg[r[i].x - (unsigned)nbase], 1);
    __syncthreads();
    int d0 = sdeg[t], d1 = sdeg[t + 256];
    int q0 = (d0 + 7) & ~7, q1 = (d1 + 7) & ~7;  // padded degrees
    pofs[t] = q0;
    pofs[t + 256] = q1;
    __syncthreads();
    for (int o = 1; o < 512; o <<= 1) {
        int a = (t >= o) ? pofs[t - o] : 0;
        int b = (t + 256 >= o) ? pofs[t + 256 - o] : 0;
        __syncthreads();
        pofs[t] += a;
        pofs[t + 256] += b;
        __syncthreads();
    }
    int ex0 = pofs[t] - q0, ex1 = pofs[t + 256] - q1;
    int ptotal = pofs[511];
    lcur[t] = ex0;
    lcur[t + 256] = ex1;
    if (t < nn) { rp[nbase + t] = cbase + ex0; deg_out[nbase + t] = d0; }
    if (t + 256 < nn) { rp[nbase + t + 256] = cbase + ex1; deg_out[nbase + t + 256] = d1; }
    if (p == NB_BKT - 1 && t == 0) rp[n] = cbase + ptotal;
    // pre-fill everything with phantom id, then scatter real edges at range fronts
    for (int i = t; i < ptotal; i += 256) lcol[i] = n;
    __syncthreads();
    for (int i = t; i < cnt; i += 256) {
        uint2 e = r[i];
        int slot = atomicAdd(&lcur[e.x - (unsigned)nbase], 1);
        lcol[slot] = (int)e.y;
    }
    __syncthreads();
    for (int i = t; i < ptotal; i += 256) col[cbase + i] = lcol[i];
}

// ---------------- Layer 1 (din=6, dout=16): one thread per node, fp32 in, f16 out ----------------
// Uses true degree (never touches phantom slots; feat has no phantom row).

__global__ __launch_bounds__(256) void sage_layer1(const float* __restrict__ feat,
                                                   const int* __restrict__ rp,
                                                   const int* __restrict__ deg,
                                                   const int* __restrict__ col,
                                                   const float* __restrict__ W,
                                                   const float* __restrict__ bias,
                                                   unsigned int* __restrict__ hout, int n) {
    __shared__ float sW[6 * 16];
    __shared__ float sB[16];
    int tid = threadIdx.x;
    if (tid < 96) sW[tid] = W[tid];
    if (tid < 16) sB[tid] = bias[tid];
    __syncthreads();
    int v = blockIdx.x * 256 + tid;
    if (v >= n) return;
    int r0 = rp[v];
    int dg = deg[v];
    int r1 = r0 + dg;
    float acc[6] = {0.f, 0.f, 0.f, 0.f, 0.f, 0.f};
    const float2* f2 = reinterpret_cast<const float2*>(feat);
    int j = r0;
    for (; j + 4 <= r1; j += 4) {
        int u0 = col[j], u1 = col[j + 1], u2 = col[j + 2], u3 = col[j + 3];
        float2 a0 = f2[u0 * 3 + 0], b0 = f2[u0 * 3 + 1], c0 = f2[u0 * 3 + 2];
        float2 a1 = f2[u1 * 3 + 0], b1 = f2[u1 * 3 + 1], c1 = f2[u1 * 3 + 2];
        float2 a2 = f2[u2 * 3 + 0], b2 = f2[u2 * 3 + 1], c2 = f2[u2 * 3 + 2];
        float2 a3 = f2[u3 * 3 + 0], b3 = f2[u3 * 3 + 1], c3 = f2[u3 * 3 + 2];
        acc[0] += (a0.x + a1.x) + (a2.x + a3.x);
        acc[1] += (a0.y + a1.y) + (a2.y + a3.y);
        acc[2] += (b0.x + b1.x) + (b2.x + b3.x);
        acc[3] += (b0.y + b1.y) + (b2.y + b3.y);
        acc[4] += (c0.x + c1.x) + (c2.x + c3.x);
        acc[5] += (c0.y + c1.y) + (c2.y + c3.y);
    }
    for (; j < r1; ++j) {
        int u = col[j];
        float2 a = f2[u * 3 + 0], b = f2[u * 3 + 1], c = f2[u * 3 + 2];
        acc[0] += a.x; acc[1] += a.y;
        acc[2] += b.x; acc[3] += b.y;
        acc[4] += c.x; acc[5] += c.y;
    }
    {
        float2 a = f2[v * 3 + 0], b = f2[v * 3 + 1], c = f2[v * 3 + 2];
        acc[0] += a.x; acc[1] += a.y;
        acc[2] += b.x; acc[3] += b.y;
        acc[4] += c.x; acc[5] += c.y;
    }
    float inv = 1.0f / (float)(dg + 1);
#pragma unroll
    for (int k = 0; k < 6; ++k) acc[k] *= inv;
    float outv[16];
#pragma unroll
    for (int o = 0; o < 16; ++o) outv[o] = sB[o];
#pragma unroll
    for (int k = 0; k < 6; ++k) {
#pragma unroll
        for (int o = 0; o < 16; ++o) outv[o] += acc[k] * sW[k * 16 + o];
    }
    unsigned int w[8];
#pragma unroll
    for (int o = 0; o < 16; o += 2)
        w[o / 2] = packh2(fmaxf(outv[o], 0.f), fmaxf(outv[o + 1], 0.f));
    uint4* op = reinterpret_cast<uint4*>(hout + v * 8);
    op[0] = make_uint4(w[0], w[1], w[2], w[3]);
    op[1] = make_uint4(w[4], w[5], w[6], w[7]);
}

// ---------------- Generic fused layer, f16, double-buffered 8-edge batches ----------------
// Edge lists padded to mult of 8 with phantom node (zero row). Cols load as int4.

template <int DIN, int DOUT>
__global__ __launch_bounds__(256) void sage_f16(const uint4* __restrict__ hin,
                                                const int* __restrict__ rp,
                                                const int* __restrict__ deg,
                                                const int* __restrict__ col,
                                                const float* __restrict__ W,
                                                const float* __restrict__ bias,
                                                unsigned int* __restrict__ hout, int n) {
    constexpr int WPN = DIN / 8;
    constexpr int NPB = 256 / WPN;
    constexpr int OPT = DOUT / WPN;
    __shared__ float sW[DIN * DOUT];
    __shared__ float sB[DOUT];
    __shared__ float sH[NPB][DIN + 1];

    int tid = threadIdx.x;
    for (int i = tid; i < DIN * DOUT; i += 256) sW[i] = W[i];
    if (tid < DOUT) sB[tid] = bias[tid];

    int sub = tid / WPN;
    int t = tid % WPN;
    int v = blockIdx.x * NPB + sub;

    if (v < n) {
        int r0 = rp[v];
        int dg = deg[v];
        int nb = (dg + 7) >> 3;  // padded batch count
        const __half2 z = __float2half2_rn(0.f);
        __half2 accA[4] = {z, z, z, z}, accB[4] = {z, z, z, z};
        uint4 wA[8], wB[8];

        auto issue8 = [&](int jj, uint4* w) {
            int4 cA = *reinterpret_cast<const int4*>(col + jj);
            int4 cB = *reinterpret_cast<const int4*>(col + jj + 4);
            w[0] = hin[cA.x * WPN + t];
            w[1] = hin[cA.y * WPN + t];
            w[2] = hin[cA.z * WPN + t];
            w[3] = hin[cA.w * WPN + t];
            w[4] = hin[cB.x * WPN + t];
            w[5] = hin[cB.y * WPN + t];
            w[6] = hin[cB.z * WPN + t];
            w[7] = hin[cB.w * WPN + t];
        };
        auto acc8 = [&](const uint4* w, __half2* a) {
#pragma unroll
            for (int k = 0; k < 8; ++k) {
                a[0] = __hadd2(a[0], u2h(w[k].x));
                a[1] = __hadd2(a[1], u2h(w[k].y));
                a[2] = __hadd2(a[2], u2h(w[k].z));
                a[3] = __hadd2(a[3], u2h(w[k].w));
            }
        };

        int j = r0;
        if (nb > 0) {
            issue8(j, wA);
            j += 8;
            int remaining = nb - 1;
            while (remaining >= 2) {
                issue8(j, wB); j += 8;
                acc8(wA, accA);
                issue8(j, wA); j += 8;
                acc8(wB, accB);
                remaining -= 2;
            }
            if (remaining == 1) {
                issue8(j, wB);
                acc8(wA, accA);
                acc8(wB, accB);
            } else {
                acc8(wA, accA);
            }
        }
#pragma unroll
        for (int q = 0; q < 4; ++q) accA[q] = __hadd2(accA[q], accB[q]);
        uint4 ws = hin[v * WPN + t];
        unsigned swd[4] = {ws.x, ws.y, ws.z, ws.w};
        float inv = 1.0f / (float)(dg + 1);
#pragma unroll
        for (int q = 0; q < 4; ++q) {
            float2 f = __half22float2(accA[q]);
            float2 s = u2f2(swd[q]);
            sH[sub][t * 8 + 2 * q + 0] = (f.x + s.x) * inv;
            sH[sub][t * 8 + 2 * q + 1] = (f.y + s.y) * inv;
        }
    }
    __syncthreads();
    if (v < n) {
        int o0 = t * OPT;
        float accO[OPT];
#pragma unroll
        for (int i = 0; i < OPT; ++i) accO[i] = sB[o0 + i];
#pragma unroll 4
        for (int k = 0; k < DIN; ++k) {
            float hk = sH[sub][k];
#pragma unroll
            for (int i = 0; i < OPT; ++i) accO[i] += hk * sW[k * DOUT + o0 + i];
        }
        unsigned wds[OPT / 2];
#pragma unroll
        for (int i = 0; i < OPT; i += 2)
            wds[i / 2] = packh2(fmaxf(accO[i], 0.f), fmaxf(accO[i + 1], 0.f));
        unsigned* op = hout + v * (DOUT / 2) + o0 / 2;
        if constexpr (OPT / 2 == 4) {
            *reinterpret_cast<uint4*>(op) = make_uint4(wds[0], wds[1], wds[2], wds[3]);
        } else if constexpr (OPT / 2 == 8) {
            reinterpret_cast<uint4*>(op)[0] = make_uint4(wds[0], wds[1], wds[2], wds[3]);
            reinterpret_cast<uint4*>(op)[1] = make_uint4(wds[4], wds[5], wds[6], wds[7]);
        } else {
            *reinterpret_cast<uint2*>(op) = make_uint2(wds[0], wds[1]);
        }
    }
}

// ---------------- Pooling: per-graph mean, f16 input ----------------

__device__ __forceinline__ int lower_bound_i(const int* __restrict__ a, int n, int key) {
    int lo = 0, hi = n;
    while (lo < hi) {
        int m = (lo + hi) >> 1;
        if (a[m] < key) lo = m + 1; else hi = m;
    }
    return lo;
}

__global__ __launch_bounds__(256) void pool_f16(const unsigned int* __restrict__ h32,
                                                const int* __restrict__ gids,
                                                float* __restrict__ out, int n) {
    int bx = blockIdx.x;
    int g = bx >> 3, s = bx & 7;
    int start = lower_bound_i(gids, n, g);
    int end = lower_bound_i(gids, n, g + 1);
    int len = end - start;
    float inv = 1.0f / (float)(len > 0 ? len : 1);
    int chunk = (len + 7) / 8;
    int s0 = start + s * chunk;
    int s1 = min(s0 + chunk, end);
    int t = threadIdx.x;
    int d = t & 31, j = t >> 5;
    float a0 = 0.f, a1 = 0.f;
    for (int i = s0 + j; i < s1; i += 8) {
        float2 f = u2f2(h32[(size_t)i * 32 + d]);
        a0 += f.x;
        a1 += f.y;
    }
    __shared__ float red[8][32][2];
    red[j][d][0] = a0;
    red[j][d][1] = a1;
    __syncthreads();
    if (t < 64) {
        int dd = t & 31, e = t >> 5;
        float tot = 0.f;
#pragma unroll
        for (int k = 0; k < 8; ++k) tot += red[k][dd][e];
        atomicAdd(&out[g * 64 + 2 * dd + e], tot * inv);
    }
}

// ---------------- launch ----------------

extern "C" void kernel_launch(void* const* d_in, const int* in_sizes, int n_in,
                              void* d_out, int out_size, void* d_ws, size_t ws_size,
                              hipStream_t stream) {
    const int N = N_NODES, E = N_EDGES;
    const float* feat = (const float*)d_in[0];
    const int* src = (const int*)d_in[1];
    const int* dst = (const int*)d_in[2];
    const int* gids = (const int*)d_in[3];
    const float* W1 = (const float*)d_in[4];
    const float* b1 = (const float*)d_in[5];
    const float* W2 = (const float*)d_in[6];
    const float* b2 = (const float*)d_in[7];
    const float* W3 = (const float*)d_in[8];
    const float* b3 = (const float*)d_in[9];
    const float* W4 = (const float*)d_in[10];
    const float* b4 = (const float*)d_in[11];
    float* out = (float*)d_out;

    // workspace layout
    int* rp = (int*)d_ws;                        // N+1
    int* deg = rp + (N + 1);                     // N
    int* gcnt = deg + N;                         // 256
    int* cntmat = gcnt + 256;                    // NBLK_BIN*256
    int* col = cntmat + (size_t)NBLK_BIN * 256;  // padded CSR
    size_t colsz = (size_t)(((E + 7) & ~7) + NB_BKT * BKT_SLACK + 8);
    size_t off = (size_t)((char*)(col + colsz) - (char*)d_ws);
    off = (off + 255) & ~(size_t)255;
    unsigned int* h1 = (unsigned int*)((char*)d_ws + off);   // f16 (N+1)*16
    unsigned int* h2 = h1 + (size_t)(N + 1) * 8;             // f16 (N+1)*32
    unsigned int* h3 = h2 + (size_t)(N + 1) * 16;            // f16 (N+1)*64
    unsigned int* h4 = h3 + (size_t)(N + 1) * 32;            // f16 N*64
    uint2* rec = (uint2*)h3;  // E uint2 = (N)*32 words; phantom row at word N*32 untouched

    hipMemsetAsync(out, 0, (size_t)N_GRAPHS * 64 * sizeof(float), stream);
    // zero phantom rows (node N) of h1..h3
    hipMemsetAsync(h1 + (size_t)N * 8, 0, 8 * sizeof(unsigned), stream);
    hipMemsetAsync(h2 + (size_t)N * 16, 0, 16 * sizeof(unsigned), stream);
    hipMemsetAsync(h3 + (size_t)N * 32, 0, 32 * sizeof(unsigned), stream);

    bin_count<<<NBLK_BIN, 256, 0, stream>>>(dst, cntmat, E);
    bin_scan<<<NB_BKT, 256, 0, stream>>>(cntmat, gcnt, NBLK_BIN);
    bin_write<<<NBLK_BIN, 256, 0, stream>>>(dst, src, cntmat, gcnt, rec, E);
    fill_bucket<<<NB_BKT, 256, 0, stream>>>(rec, gcnt, rp, deg, col, N);

    sage_layer1<<<(N + 255) / 256, 256, 0, stream>>>(feat, rp, deg, col, W1, b1, h1, N);
    // layer2: DIN=16 WPN=2 NPB=128
    sage_f16<16, 32><<<(N + 127) / 128, 256, 0, stream>>>(
        (const uint4*)h1, rp, deg, col, W2, b2, h2, N);
    // layer3: DIN=32 WPN=4 NPB=64
    sage_f16<32, 64><<<(N + 63) / 64, 256, 0, stream>>>(
        (const uint4*)h2, rp, deg, col, W3, b3, h3, N);
    // layer4: DIN=64 WPN=8 NPB=32
    sage_f16<64, 64><<<(N + 31) / 32, 256, 0, stream>>>(
        (const uint4*)h3, rp, deg, col, W4, b4, h4, N);

    pool_f16<<<N_GRAPHS * 8, 256, 0, stream>>>(h4, gids, out, N);
}